// Round 4
// baseline (252.230 us; speedup 1.0000x reference)
//
#include <hip/hip_runtime.h>

typedef _Float16 f16;
typedef f16 half8 __attribute__((ext_vector_type(8)));
typedef f16 f16x4 __attribute__((ext_vector_type(4)));
typedef float f32x4 __attribute__((ext_vector_type(4)));

#define GLOAD_LDS16(gsrc, ldst)                                                              \
  __builtin_amdgcn_global_load_lds((const __attribute__((address_space(1))) void*)(gsrc),    \
                                   (__attribute__((address_space(3))) void*)(ldst), 16, 0, 0)

constexpr float SCALE = 0.125f;  // 64^-0.5
// Q pre-scale folds log2(e) so softmax runs in exp2 domain (raw v_exp_f32).
constexpr float SCALE_L2E = 0.125f * 1.4426950408889634f;

static __device__ __forceinline__ f32x4 vmax4(f32x4 a, f32x4 b) {
  f32x4 r;
  r[0] = fmaxf(a[0], b[0]); r[1] = fmaxf(a[1], b[1]);
  r[2] = fmaxf(a[2], b[2]); r[3] = fmaxf(a[3], b[3]);
  return r;
}

// ---------------- convert f32 -> f16, vectorized x4 ----------------
__global__ __launch_bounds__(256) void k_cvt(const float4* __restrict__ in,
                                             f16x4* __restrict__ out, int n4) {
  int i = blockIdx.x * 256 + threadIdx.x;
  if (i < n4) {
    float4 v = in[i];
    f16x4 o;
    o[0] = (f16)v.x; o[1] = (f16)v.y; o[2] = (f16)v.z; o[3] = (f16)v.w;
    out[i] = o;
  }
}

// ---------------- transpose f32 [R][C] -> f16 [C][R] (generic, for W_out) ----
__global__ __launch_bounds__(256) void k_transpose(const float* __restrict__ in,
                                                   f16* __restrict__ out, int R, int C) {
  __shared__ float t[32][33];
  int c0 = blockIdx.x * 32, r0 = blockIdx.y * 32;
  int tx = threadIdx.x, ty = threadIdx.y;
  for (int i = ty; i < 32; i += 8) t[i][tx] = in[(size_t)(r0 + i) * C + c0 + tx];
  __syncthreads();
  for (int i = ty; i < 32; i += 8) out[(size_t)(c0 + i) * R + r0 + tx] = (f16)t[tx][i];
}

// -------- W_qkv transpose with column-permuted output row order ----------
// out row e' = k*1024 + h*64 + d  (kills epilogue write amplification).
__global__ __launch_bounds__(256) void k_transpose_qkv(const float* __restrict__ in,
                                                       f16* __restrict__ out) {
  __shared__ float t[32][33];
  int c0 = blockIdx.x * 32, r0 = blockIdx.y * 32;
  int tx = threadIdx.x, ty = threadIdx.y;
  for (int i = ty; i < 32; i += 8) t[i][tx] = in[(size_t)(r0 + i) * 3072 + c0 + tx];
  __syncthreads();
  for (int i = ty; i < 32; i += 8) {
    const int e = c0 + i;
    const int d = e / 48, rem = e - d * 48;
    const int k = rem >> 4, h = rem & 15;
    const int ep = k * 1024 + h * 64 + d;
    out[(size_t)ep * 1024 + r0 + tx] = (f16)t[tx][i];
  }
}

// ---------------- GEMM (unchanged from round 3) ----------------
template <int MODE>
__global__ __launch_bounds__(256) void k_gemm(const f16* __restrict__ A,
                                              const f16* __restrict__ Bt,
                                              float* __restrict__ C,
                                              f16* __restrict__ Qp,
                                              f16* __restrict__ Kp,
                                              f16* __restrict__ Vt) {
  constexpr int K = 1024, BK = 64;
  __shared__ alignas(16) f16 smem[128 * 128];
  f16* As = smem;
  f16* Bs = smem + 128 * 64;
  const int tid = threadIdx.x;
  const int w = tid >> 6, lane = tid & 63;
  const int g = lane >> 4, lr = lane & 15;
  const int wr = w >> 1, wc = w & 1;
  const int m0 = blockIdx.y * 128, n0 = blockIdx.x * 128;
  const int srow = lane >> 3;
  const int scol = ((lane & 7) ^ srow) << 3;

  f32x4 acc[4][4] = {};

  for (int kt = 0; kt < K; kt += BK) {
    __syncthreads();
#pragma unroll
    for (int i = 0; i < 4; ++i) {
      const int chunk = w * 4 + i;
      const int row = chunk * 8 + srow;
      GLOAD_LDS16(A + (size_t)(m0 + row) * K + kt + scol, &As[chunk * 512]);
      GLOAD_LDS16(Bt + (size_t)(n0 + row) * K + kt + scol, &Bs[chunk * 512]);
    }
    __syncthreads();
#pragma unroll
    for (int c = 0; c < 2; ++c) {
      half8 af[4], bf[4];
#pragma unroll
      for (int m = 0; m < 4; ++m) {
        const int ra = wr * 64 + m * 16 + lr;
        const int off = ra * 128 + ((((c << 2) | g) ^ (ra & 7)) << 4);
        af[m] = *(const half8*)((const char*)As + off);
      }
#pragma unroll
      for (int n = 0; n < 4; ++n) {
        const int rb = wc * 64 + n * 16 + lr;
        const int off = rb * 128 + ((((c << 2) | g) ^ (rb & 7)) << 4);
        bf[n] = *(const half8*)((const char*)Bs + off);
      }
#pragma unroll
      for (int m = 0; m < 4; ++m)
#pragma unroll
        for (int n = 0; n < 4; ++n)
          acc[m][n] = __builtin_amdgcn_mfma_f32_16x16x32_f16(af[m], bf[n], acc[m][n], 0, 0, 0);
    }
  }

  if constexpr (MODE == 0) {
    const int sec = n0 >> 10;
    const int base = n0 & 1023;
    const int b = m0 >> 11;
    if (sec < 2) {
      f16* __restrict__ dst = (sec == 0) ? Qp : Kp;
      const float mul = (sec == 0) ? SCALE_L2E : 1.0f;
#pragma unroll
      for (int n = 0; n < 4; ++n) {
        const int idx = base + wc * 64 + n * 16 + lr;
        const int h = idx >> 6, d = idx & 63;
        f16* __restrict__ dh = dst + ((size_t)(b * 16 + h) * 2048) * 64 + d;
#pragma unroll
        for (int m = 0; m < 4; ++m)
#pragma unroll
          for (int r = 0; r < 4; ++r) {
            const int nn = (m0 & 2047) + wr * 64 + m * 16 + 4 * g + r;
            dh[(size_t)nn * 64] = (f16)(acc[m][n][r] * mul);
          }
      }
    } else {
      char* sb = (char*)smem;
      __syncthreads();
#pragma unroll
      for (int m = 0; m < 4; ++m)
#pragma unroll
        for (int n = 0; n < 4; ++n) {
          const int col = wc * 64 + n * 16 + lr;
          const int tok0 = wr * 64 + m * 16 + 4 * g;
          f16x4 v4;
#pragma unroll
          for (int r = 0; r < 4; ++r) v4[r] = (f16)acc[m][n][r];
          *(f16x4*)(sb + col * 256 + ((tok0 * 2) ^ ((col & 15) << 4))) = v4;
        }
      __syncthreads();
      const int nn0 = m0 & 2047;
#pragma unroll
      for (int pass = 0; pass < 8; ++pass) {
        const int c = w * 32 + pass * 4 + g;
        const int idx = base + c;
        const int h = idx >> 6, d = idx & 63;
        const half8 v = *(const half8*)(sb + c * 256 + ((lr * 16) ^ ((c & 15) << 4)));
        *(half8*)(Vt + ((size_t)(b * 16 + h) * 64 + d) * 2048 + nn0 + lr * 8) = v;
      }
    }
  } else {
#pragma unroll
    for (int m = 0; m < 4; ++m)
#pragma unroll
      for (int n = 0; n < 4; ++n)
#pragma unroll
        for (int r = 0; r < 4; ++r)
          C[(size_t)(m0 + wr * 64 + m * 16 + 4 * g + r) * 1024 +
            (n0 + wc * 64 + n * 16 + lr)] = acc[m][n][r];
  }
}

// ---------------- causal flash attention v3: swapped QK^T, in-lane softmax ----
// 1-wave blocks (64 thr). Each wave: 32 q-rows (2 frags), 64-key tiles.
// Swapped mfma(K,Q) -> lane holds S^T[key][q=lr]: softmax is in-lane tree +
// 2 single-depth shfl_xor(16/32). exp2 domain (log2e folded into Q scale).
// Grid: XCD-chunked (4 heads/XCD -> K/V L2-resident) + LPT (long t first).
__global__ __launch_bounds__(64, 3) void k_attn(const f16* __restrict__ Q,
                                                const f16* __restrict__ Kp,
                                                const f16* __restrict__ Vt,
                                                f16* __restrict__ O) {
  __shared__ alignas(16) f16 plds[2][16][72];
  const int lane = threadIdx.x;
  const int g = lane >> 4, lr = lane & 15;
  const int id = (blockIdx.x & 7) * 256 + (blockIdx.x >> 3);  // XCD-chunked
  const int bh = id >> 6;
  const int t = 63 - (id & 63);  // LPT: longest causal blocks first
  const int q0 = t * 32;

  const f16* __restrict__ Qb = Q + (size_t)bh * (2048 * 64);
  const f16* __restrict__ Kb = Kp + (size_t)bh * (2048 * 64);
  const f16* __restrict__ Vb = Vt + (size_t)bh * (64 * 2048);

  // Q fragments (B-operand of swapped QK): col=lr -> q-row, k=8g+i
  half8 qf[2][2];
#pragma unroll
  for (int f = 0; f < 2; ++f)
#pragma unroll
    for (int c = 0; c < 2; ++c)
      qf[f][c] = *(const half8*)(Qb + (size_t)(q0 + 16 * f + lr) * 64 + 32 * c + 8 * g);

  f32x4 acc[2][4] = {};
  float mrow[2] = {-INFINITY, -INFINITY};  // running max for q-row = lr (per frag)
  float lrow[2] = {0.f, 0.f};

  const int ntiles = (q0 >> 6) + 1;

  // K tile 0 preload (A-operand: row=lr=key, k=8g+i)
  half8 kc[4][2], kn[4][2];
#pragma unroll
  for (int j = 0; j < 4; ++j)
#pragma unroll
    for (int c = 0; c < 2; ++c)
      kc[j][c] = *(const half8*)(Kb + (size_t)(16 * j + lr) * 64 + 32 * c + 8 * g);

  for (int kt = 0; kt < ntiles; ++kt) {
    const int k0 = kt * 64;
    // prefetch next K tile
    const int knext = (kt + 1 < ntiles ? kt + 1 : kt) * 64;
#pragma unroll
    for (int j = 0; j < 4; ++j)
#pragma unroll
      for (int c = 0; c < 2; ++c)
        kn[j][c] = *(const half8*)(Kb + (size_t)(knext + 16 * j + lr) * 64 + 32 * c + 8 * g);

    // ---- S^T = K Q^T : lane holds S^T[key=16j+4g+r][q=lr] ----
    __builtin_amdgcn_s_setprio(1);
    f32x4 st[2][4];
#pragma unroll
    for (int f = 0; f < 2; ++f)
#pragma unroll
      for (int j = 0; j < 4; ++j) {
        f32x4 z = {};
        z = __builtin_amdgcn_mfma_f32_16x16x32_f16(kc[j][0], qf[f][0], z, 0, 0, 0);
        st[f][j] = __builtin_amdgcn_mfma_f32_16x16x32_f16(kc[j][1], qf[f][1], z, 0, 0, 0);
      }
    __builtin_amdgcn_s_setprio(0);

    // V loads for this tile (latency hides under softmax)
    half8 va[4][2];
#pragma unroll
    for (int nb = 0; nb < 4; ++nb)
#pragma unroll
      for (int c = 0; c < 2; ++c)
        va[nb][c] = *(const half8*)(Vb + (size_t)(16 * nb + lr) * 2048 + k0 + 32 * c + 8 * g);

    // causal mask
    if (k0 + 63 > q0) {
#pragma unroll
      for (int f = 0; f < 2; ++f)
#pragma unroll
        for (int j = 0; j < 4; ++j) {
          const int keyb = k0 + 16 * j + 4 * g;
          const int q = q0 + 16 * f + lr;
#pragma unroll
          for (int r = 0; r < 4; ++r)
            if (keyb + r > q) st[f][j][r] = -INFINITY;
        }
    }

    // ---- in-lane online softmax (exp2 domain), per frag ----
    float sfv[2];
#pragma unroll
    for (int f = 0; f < 2; ++f) {
      f32x4 m4 = vmax4(vmax4(st[f][0], st[f][1]), vmax4(st[f][2], st[f][3]));
      float tm = fmaxf(fmaxf(m4[0], m4[1]), fmaxf(m4[2], m4[3]));
      tm = fmaxf(tm, __shfl_xor(tm, 16));
      tm = fmaxf(tm, __shfl_xor(tm, 32));
      const float mn = fmaxf(mrow[f], tm);
      sfv[f] = __builtin_amdgcn_exp2f(mrow[f] - mn);
      mrow[f] = mn;
#pragma unroll
      for (int j = 0; j < 4; ++j)
#pragma unroll
        for (int r = 0; r < 4; ++r)
          st[f][j][r] = __builtin_amdgcn_exp2f(st[f][j][r] - mn);
      f32x4 s4 = st[f][0] + st[f][1] + st[f][2] + st[f][3];
      float rs = (s4[0] + s4[1]) + (s4[2] + s4[3]);
      rs += __shfl_xor(rs, 16);
      rs += __shfl_xor(rs, 32);
      lrow[f] = lrow[f] * sfv[f] + rs;
      // write P^T -> P via LDS: plds[f][q=lr][key], packed 4 keys (r=0..3)
#pragma unroll
      for (int j = 0; j < 4; ++j) {
        f16x4 v4;
#pragma unroll
        for (int r = 0; r < 4; ++r) v4[r] = (f16)st[f][j][r];
        *(f16x4*)(&plds[f][lr][16 * j + 4 * g]) = v4;
      }
    }

    // rescale acc (acc row q = 4g+r; sf lives on lane lr = 4g+r)
#pragma unroll
    for (int f = 0; f < 2; ++f)
#pragma unroll
      for (int r = 0; r < 4; ++r) {
        const float sb = __shfl(sfv[f], 4 * g + r);
#pragma unroll
        for (int nb = 0; nb < 4; ++nb) acc[f][nb][r] *= sb;
      }

    asm volatile("s_waitcnt lgkmcnt(0)" ::: "memory");
    __builtin_amdgcn_sched_barrier(0);
    half8 pf[2][2];
#pragma unroll
    for (int f = 0; f < 2; ++f)
#pragma unroll
      for (int c = 0; c < 2; ++c)
        pf[f][c] = *(const half8*)(&plds[f][lr][32 * c + 8 * g]);

    __builtin_amdgcn_s_setprio(1);
#pragma unroll
    for (int f = 0; f < 2; ++f)
#pragma unroll
      for (int nb = 0; nb < 4; ++nb) {
        acc[f][nb] = __builtin_amdgcn_mfma_f32_16x16x32_f16(pf[f][0], va[nb][0], acc[f][nb], 0, 0, 0);
        acc[f][nb] = __builtin_amdgcn_mfma_f32_16x16x32_f16(pf[f][1], va[nb][1], acc[f][nb], 0, 0, 0);
      }
    __builtin_amdgcn_s_setprio(0);
    __builtin_amdgcn_sched_barrier(0);  // keep P reads ahead of next tile's writes

#pragma unroll
    for (int j = 0; j < 4; ++j)
#pragma unroll
      for (int c = 0; c < 2; ++c)
        kc[j][c] = kn[j][c];
  }

  const int b = bh >> 4, h = bh & 15;
#pragma unroll
  for (int f = 0; f < 2; ++f)
#pragma unroll
    for (int r = 0; r < 4; ++r) {
      const float lb = __shfl(lrow[f], 4 * g + r);
      const float inv = 1.f / lb;
      const int q = q0 + 16 * f + 4 * g + r;
      f16* orow = O + ((size_t)(b * 2048 + q) * 1024) + h * 64;
#pragma unroll
      for (int nb = 0; nb < 4; ++nb) orow[16 * nb + lr] = (f16)(acc[f][nb][r] * inv);
    }
}

extern "C" void kernel_launch(void* const* d_in, const int* in_sizes, int n_in,
                              void* d_out, int out_size, void* d_ws, size_t ws_size,
                              hipStream_t stream) {
  const float* x = (const float*)d_in[0];     // [2][2048][1024]
  const float* Wqkv = (const float*)d_in[1];  // [1024][3072]
  const float* Wout = (const float*)d_in[2];  // [1024][1024]

  char* p = (char*)d_ws;
  f16* Xb = (f16*)p;    p += (size_t)4096 * 1024 * 2;      // x in f16
  f16* Wqkvt = (f16*)p; p += (size_t)3072 * 1024 * 2;      // W_qkv^T f16, rows e'=[k][h][d]
  f16* Woutt = (f16*)p; p += (size_t)1024 * 1024 * 2;      // W_out^T f16
  f16* Qp = (f16*)p;    p += (size_t)32 * 2048 * 64 * 2;   // [b*h][n][d], scaled by 1/8*log2e
  f16* Kp = (f16*)p;    p += (size_t)32 * 2048 * 64 * 2;   // [b*h][n][d]
  f16* Vt = (f16*)p;    p += (size_t)32 * 64 * 2048 * 2;   // [b*h][d][n]
  f16* O = (f16*)p;     p += (size_t)4096 * 1024 * 2;      // [b*n][h*64+d]

  k_cvt<<<4096, 256, 0, stream>>>((const float4*)x, (f16x4*)Xb, 4096 * 1024 / 4);
  k_transpose_qkv<<<dim3(96, 32), dim3(32, 8), 0, stream>>>(Wqkv, Wqkvt);
  k_transpose<<<dim3(32, 32), dim3(32, 8), 0, stream>>>(Wout, Woutt, 1024, 1024);
  k_gemm<0><<<dim3(24, 32), 256, 0, stream>>>(Xb, Wqkvt, nullptr, Qp, Kp, Vt);
  k_attn<<<2048, 64, 0, stream>>>(Qp, Kp, Vt, O);
  k_gemm<1><<<dim3(8, 32), 256, 0, stream>>>(O, Woutt, (float*)d_out, nullptr, nullptr, nullptr);
}

// Round 6
// 230.285 us; speedup vs baseline: 1.0953x; 1.0953x over previous
//
#include <hip/hip_runtime.h>

typedef _Float16 f16;
typedef f16 half8 __attribute__((ext_vector_type(8)));
typedef f16 f16x4 __attribute__((ext_vector_type(4)));
typedef float f32x4 __attribute__((ext_vector_type(4)));

#define GLOAD_LDS16(gsrc, ldst)                                                              \
  __builtin_amdgcn_global_load_lds((const __attribute__((address_space(1))) void*)(gsrc),    \
                                   (__attribute__((address_space(3))) void*)(ldst), 16, 0, 0)

// sched_barrier-wrapped raw barrier: no vmcnt(0) drain (unlike __syncthreads),
// sched fences stop hipcc moving ds/vm ops across it (rule #18).
#define WGBAR()                            \
  do {                                     \
    __builtin_amdgcn_sched_barrier(0);     \
    __builtin_amdgcn_s_barrier();          \
    __builtin_amdgcn_sched_barrier(0);     \
  } while (0)

constexpr float SCALE = 0.125f;  // 64^-0.5
// Q pre-scale folds log2(e): softmax runs in exp2 domain (raw v_exp_f32).
constexpr float SCALE_L2E = 0.125f * 1.4426950408889634f;

// ---------------- convert f32 -> f16, vectorized x4 ----------------
__global__ __launch_bounds__(256) void k_cvt(const float4* __restrict__ in,
                                             f16x4* __restrict__ out, int n4) {
  int i = blockIdx.x * 256 + threadIdx.x;
  if (i < n4) {
    float4 v = in[i];
    f16x4 o;
    o[0] = (f16)v.x; o[1] = (f16)v.y; o[2] = (f16)v.z; o[3] = (f16)v.w;
    out[i] = o;
  }
}

// ---------------- transpose f32 [R][C] -> f16 [C][R] (generic, for W_out) ----
__global__ __launch_bounds__(256) void k_transpose(const float* __restrict__ in,
                                                   f16* __restrict__ out, int R, int C) {
  __shared__ float t[32][33];
  int c0 = blockIdx.x * 32, r0 = blockIdx.y * 32;
  int tx = threadIdx.x, ty = threadIdx.y;
  for (int i = ty; i < 32; i += 8) t[i][tx] = in[(size_t)(r0 + i) * C + c0 + tx];
  __syncthreads();
  for (int i = ty; i < 32; i += 8) out[(size_t)(c0 + i) * R + r0 + tx] = (f16)t[tx][i];
}

// -------- W_qkv transpose with column-permuted output row order ----------
// out row e' = k*1024 + h*64 + d  (kills epilogue write amplification).
__global__ __launch_bounds__(256) void k_transpose_qkv(const float* __restrict__ in,
                                                       f16* __restrict__ out) {
  __shared__ float t[32][33];
  int c0 = blockIdx.x * 32, r0 = blockIdx.y * 32;
  int tx = threadIdx.x, ty = threadIdx.y;
  for (int i = ty; i < 32; i += 8) t[i][tx] = in[(size_t)(r0 + i) * 3072 + c0 + tx];
  __syncthreads();
  for (int i = ty; i < 32; i += 8) {
    const int e = c0 + i;
    const int d = e / 48, rem = e - d * 48;
    const int k = rem >> 4, h = rem & 15;
    const int ep = k * 1024 + h * 64 + d;
    out[(size_t)ep * 1024 + r0 + tx] = (f16)t[tx][i];
  }
}

// ---------------- GEMM (unchanged) ----------------
template <int MODE>
__global__ __launch_bounds__(256) void k_gemm(const f16* __restrict__ A,
                                              const f16* __restrict__ Bt,
                                              float* __restrict__ C,
                                              f16* __restrict__ Qp,
                                              f16* __restrict__ Kp,
                                              f16* __restrict__ Vt) {
  constexpr int K = 1024, BK = 64;
  __shared__ alignas(16) f16 smem[128 * 128];
  f16* As = smem;
  f16* Bs = smem + 128 * 64;
  const int tid = threadIdx.x;
  const int w = tid >> 6, lane = tid & 63;
  const int g = lane >> 4, lr = lane & 15;
  const int wr = w >> 1, wc = w & 1;
  const int m0 = blockIdx.y * 128, n0 = blockIdx.x * 128;
  const int srow = lane >> 3;
  const int scol = ((lane & 7) ^ srow) << 3;

  f32x4 acc[4][4] = {};

  for (int kt = 0; kt < K; kt += BK) {
    __syncthreads();
#pragma unroll
    for (int i = 0; i < 4; ++i) {
      const int chunk = w * 4 + i;
      const int row = chunk * 8 + srow;
      GLOAD_LDS16(A + (size_t)(m0 + row) * K + kt + scol, &As[chunk * 512]);
      GLOAD_LDS16(Bt + (size_t)(n0 + row) * K + kt + scol, &Bs[chunk * 512]);
    }
    __syncthreads();
#pragma unroll
    for (int c = 0; c < 2; ++c) {
      half8 af[4], bf[4];
#pragma unroll
      for (int m = 0; m < 4; ++m) {
        const int ra = wr * 64 + m * 16 + lr;
        const int off = ra * 128 + ((((c << 2) | g) ^ (ra & 7)) << 4);
        af[m] = *(const half8*)((const char*)As + off);
      }
#pragma unroll
      for (int n = 0; n < 4; ++n) {
        const int rb = wc * 64 + n * 16 + lr;
        const int off = rb * 128 + ((((c << 2) | g) ^ (rb & 7)) << 4);
        bf[n] = *(const half8*)((const char*)Bs + off);
      }
#pragma unroll
      for (int m = 0; m < 4; ++m)
#pragma unroll
        for (int n = 0; n < 4; ++n)
          acc[m][n] = __builtin_amdgcn_mfma_f32_16x16x32_f16(af[m], bf[n], acc[m][n], 0, 0, 0);
    }
  }

  if constexpr (MODE == 0) {
    const int sec = n0 >> 10;
    const int base = n0 & 1023;
    const int b = m0 >> 11;
    if (sec < 2) {
      f16* __restrict__ dst = (sec == 0) ? Qp : Kp;
      const float mul = (sec == 0) ? SCALE_L2E : 1.0f;
#pragma unroll
      for (int n = 0; n < 4; ++n) {
        const int idx = base + wc * 64 + n * 16 + lr;
        const int h = idx >> 6, d = idx & 63;
        f16* __restrict__ dh = dst + ((size_t)(b * 16 + h) * 2048) * 64 + d;
#pragma unroll
        for (int m = 0; m < 4; ++m)
#pragma unroll
          for (int r = 0; r < 4; ++r) {
            const int nn = (m0 & 2047) + wr * 64 + m * 16 + 4 * g + r;
            dh[(size_t)nn * 64] = (f16)(acc[m][n][r] * mul);
          }
      }
    } else {
      char* sb = (char*)smem;
      __syncthreads();
#pragma unroll
      for (int m = 0; m < 4; ++m)
#pragma unroll
        for (int n = 0; n < 4; ++n) {
          const int col = wc * 64 + n * 16 + lr;
          const int tok0 = wr * 64 + m * 16 + 4 * g;
          f16x4 v4;
#pragma unroll
          for (int r = 0; r < 4; ++r) v4[r] = (f16)acc[m][n][r];
          *(f16x4*)(sb + col * 256 + ((tok0 * 2) ^ ((col & 15) << 4))) = v4;
        }
      __syncthreads();
      const int nn0 = m0 & 2047;
#pragma unroll
      for (int pass = 0; pass < 8; ++pass) {
        const int c = w * 32 + pass * 4 + g;
        const int idx = base + c;
        const int h = idx >> 6, d = idx & 63;
        const half8 v = *(const half8*)(sb + c * 256 + ((lr * 16) ^ ((c & 15) << 4)));
        *(half8*)(Vt + ((size_t)(b * 16 + h) * 64 + d) * 2048 + nn0 + lr * 8) = v;
      }
    }
  } else {
#pragma unroll
    for (int m = 0; m < 4; ++m)
#pragma unroll
      for (int n = 0; n < 4; ++n)
#pragma unroll
        for (int r = 0; r < 4; ++r)
          C[(size_t)(m0 + wr * 64 + m * 16 + 4 * g + r) * 1024 +
            (n0 + wc * 64 + n * 16 + lr)] = acc[m][n][r];
  }
}

// ---------------- causal flash attention v4 ----------------
// v2's proven compute core + block-cooperative K/V LDS staging:
// 4 waves/block (q0 = t*128 + w*32), K/V tiles staged once per block via
// global_load_lds, double-buffered, counted vmcnt(4) + raw s_barrier so
// next-tile loads stay in flight across the barrier (T3/T4-lite).
// XOR-swizzled LDS (pre-swizzled global source, swizzled ds_read - rule #21).
// Uniform trip count per block; waves skip compute (not barriers) past diag.
__global__ __launch_bounds__(256, 2) void k_attn(const f16* __restrict__ Q,
                                                 const f16* __restrict__ Kp,
                                                 const f16* __restrict__ Vt,
                                                 f16* __restrict__ O) {
  __shared__ alignas(16) f16 Ks[2][4096];  // [buf][64 keys][64 d], swizzled
  __shared__ alignas(16) f16 Vs[2][4096];  // [buf][64 d][64 tok], swizzled
  __shared__ alignas(16) f16 plds_all[4][2][16][72];
  const int tid = threadIdx.x;
  const int w = tid >> 6, lane = tid & 63;
  const int g = lane >> 4, lr = lane & 15;
  const int bh = blockIdx.x & 31;
  const int u = blockIdx.x >> 5;
  const int t = (u < 8) ? u : 23 - u;  // complementary causal-load pairing
  const int q0 = t * 128 + w * 32;
  f16(*plds)[16][72] = plds_all[w];

  const f16* __restrict__ Qb = Q + (size_t)bh * (2048 * 64);
  const char* __restrict__ Kb = (const char*)(Kp + (size_t)bh * (2048 * 64));
  const char* __restrict__ Vb = (const char*)(Vt + (size_t)bh * (64 * 2048));

  half8 qf[2][2];
#pragma unroll
  for (int f = 0; f < 2; ++f)
#pragma unroll
    for (int c = 0; c < 2; ++c)
      qf[f][c] = *(const half8*)(Qb + (size_t)(q0 + 16 * f + lr) * 64 + 32 * c + 8 * g);

  f32x4 acc[2][4] = {};
  float mrow[2][4], lrow[2][4];
#pragma unroll
  for (int f = 0; f < 2; ++f)
#pragma unroll
    for (int r = 0; r < 4; ++r) {
      mrow[f][r] = -INFINITY;
      lrow[f][r] = 0.f;
    }

  const int nt = 2 * t + 2;           // uniform per block
  const int srow8 = lane >> 3;        // 0..7
  const int sc = ((lane & 7) ^ srow8) << 4;  // pre-swizzled source byte col

  // stage K/V tile k0s into buf: wave w covers LDS bytes [(p*4+w)*1024, +1024)
  auto stage = [&](int k0s, int buf) {
#pragma unroll
    for (int p = 0; p < 2; ++p) {
      const int o = (p * 4 + w) * 1024;
      const int row = (p * 4 + w) * 8 + srow8;  // key idx (K) / d idx (V)
      GLOAD_LDS16(Kb + (size_t)(k0s + row) * 128 + sc, (char*)Ks[buf] + o);
      GLOAD_LDS16(Vb + (size_t)row * 4096 + (size_t)k0s * 2 + sc, (char*)Vs[buf] + o);
    }
  };

  stage(0, 0);
  asm volatile("s_waitcnt vmcnt(0)" ::: "memory");
  WGBAR();

  for (int kt = 0; kt < nt; ++kt) {
    const int k0 = kt * 64;
    const int buf = kt & 1;
    if (kt + 1 < nt) {
      stage(k0 + 64, buf ^ 1);
      asm volatile("s_waitcnt vmcnt(4)" ::: "memory");  // tile kt landed; kt+1 in flight
    } else {
      asm volatile("s_waitcnt vmcnt(0)" ::: "memory");
    }
    WGBAR();  // tile kt visible to all waves

    if (k0 <= q0) {  // wave-uniform causal skip
      // K fragments from LDS (swizzled read; 2-way bank alias = free)
      half8 kf[4][2];
#pragma unroll
      for (int j = 0; j < 4; ++j)
#pragma unroll
        for (int c = 0; c < 2; ++c)
          kf[j][c] = *(const half8*)((const char*)Ks[buf] + (16 * j + lr) * 128 +
                                     ((64 * c + 16 * g) ^ ((lr & 7) << 4)));

      __builtin_amdgcn_s_setprio(1);
      f32x4 s[2][4];
#pragma unroll
      for (int f = 0; f < 2; ++f)
#pragma unroll
        for (int j = 0; j < 4; ++j) {
          f32x4 z = {};
          z = __builtin_amdgcn_mfma_f32_16x16x32_f16(qf[f][0], kf[j][0], z, 0, 0, 0);
          s[f][j] = __builtin_amdgcn_mfma_f32_16x16x32_f16(qf[f][1], kf[j][1], z, 0, 0, 0);
        }
      __builtin_amdgcn_s_setprio(0);

      // V fragments from LDS
      half8 va[4][2];
#pragma unroll
      for (int nb = 0; nb < 4; ++nb)
#pragma unroll
        for (int c = 0; c < 2; ++c)
          va[nb][c] = *(const half8*)((const char*)Vs[buf] + (16 * nb + lr) * 128 +
                                      ((64 * c + 16 * g) ^ ((lr & 7) << 4)));

      if (k0 + 63 > q0) {
#pragma unroll
        for (int f = 0; f < 2; ++f)
#pragma unroll
          for (int j = 0; j < 4; ++j) {
            const int key = k0 + 16 * j + lr;
#pragma unroll
            for (int r = 0; r < 4; ++r)
              if (key > q0 + 16 * f + 4 * g + r) s[f][j][r] = -INFINITY;
          }
      }

      // online softmax (exp2 domain; rows live across the 16 lanes sharing g)
#pragma unroll
      for (int f = 0; f < 2; ++f)
#pragma unroll
        for (int r = 0; r < 4; ++r) {
          float tmax = fmaxf(fmaxf(s[f][0][r], s[f][1][r]), fmaxf(s[f][2][r], s[f][3][r]));
          tmax = fmaxf(tmax, __shfl_xor(tmax, 1));
          tmax = fmaxf(tmax, __shfl_xor(tmax, 2));
          tmax = fmaxf(tmax, __shfl_xor(tmax, 4));
          tmax = fmaxf(tmax, __shfl_xor(tmax, 8));
          const float mn = fmaxf(mrow[f][r], tmax);
          const float sf = __builtin_amdgcn_exp2f(mrow[f][r] - mn);
          mrow[f][r] = mn;
          float rs = 0.f;
#pragma unroll
          for (int j = 0; j < 4; ++j) {
            const float pv = __builtin_amdgcn_exp2f(s[f][j][r] - mn);
            s[f][j][r] = pv;
            rs += pv;
          }
          rs += __shfl_xor(rs, 1);
          rs += __shfl_xor(rs, 2);
          rs += __shfl_xor(rs, 4);
          rs += __shfl_xor(rs, 8);
          lrow[f][r] = lrow[f][r] * sf + rs;
#pragma unroll
          for (int nb = 0; nb < 4; ++nb) acc[f][nb][r] *= sf;
        }

      // transpose P (D-layout) -> A-layout via wave-private LDS
#pragma unroll
      for (int f = 0; f < 2; ++f)
#pragma unroll
        for (int j = 0; j < 4; ++j)
#pragma unroll
          for (int r = 0; r < 4; ++r)
            plds[f][4 * g + r][16 * j + lr] = (f16)s[f][j][r];
      asm volatile("s_waitcnt lgkmcnt(0)" ::: "memory");
      __builtin_amdgcn_sched_barrier(0);
      half8 pf[2][2];
#pragma unroll
      for (int f = 0; f < 2; ++f)
#pragma unroll
        for (int c = 0; c < 2; ++c)
          pf[f][c] = *(const half8*)(&plds[f][lr][32 * c + 8 * g]);

      __builtin_amdgcn_s_setprio(1);
#pragma unroll
      for (int f = 0; f < 2; ++f)
#pragma unroll
        for (int nb = 0; nb < 4; ++nb) {
          acc[f][nb] =
              __builtin_amdgcn_mfma_f32_16x16x32_f16(pf[f][0], va[nb][0], acc[f][nb], 0, 0, 0);
          acc[f][nb] =
              __builtin_amdgcn_mfma_f32_16x16x32_f16(pf[f][1], va[nb][1], acc[f][nb], 0, 0, 0);
        }
      __builtin_amdgcn_s_setprio(0);
    }

    WGBAR();  // all waves done reading buf before it is restaged
  }

  const int b = bh >> 4, h = bh & 15;
#pragma unroll
  for (int f = 0; f < 2; ++f)
#pragma unroll
    for (int r = 0; r < 4; ++r) {
      const float inv = 1.f / lrow[f][r];
      const int q = q0 + 16 * f + 4 * g + r;
      f16* orow = O + ((size_t)(b * 2048 + q) * 1024) + h * 64;
#pragma unroll
      for (int nb = 0; nb < 4; ++nb) orow[16 * nb + lr] = (f16)(acc[f][nb][r] * inv);
    }
}

extern "C" void kernel_launch(void* const* d_in, const int* in_sizes, int n_in,
                              void* d_out, int out_size, void* d_ws, size_t ws_size,
                              hipStream_t stream) {
  const float* x = (const float*)d_in[0];     // [2][2048][1024]
  const float* Wqkv = (const float*)d_in[1];  // [1024][3072]
  const float* Wout = (const float*)d_in[2];  // [1024][1024]

  char* p = (char*)d_ws;
  f16* Xb = (f16*)p;    p += (size_t)4096 * 1024 * 2;      // x in f16
  f16* Wqkvt = (f16*)p; p += (size_t)3072 * 1024 * 2;      // W_qkv^T f16, rows e'=[k][h][d]
  f16* Woutt = (f16*)p; p += (size_t)1024 * 1024 * 2;      // W_out^T f16
  f16* Qp = (f16*)p;    p += (size_t)32 * 2048 * 64 * 2;   // [b*h][n][d], scaled 1/8*log2e
  f16* Kp = (f16*)p;    p += (size_t)32 * 2048 * 64 * 2;   // [b*h][n][d]
  f16* Vt = (f16*)p;    p += (size_t)32 * 64 * 2048 * 2;   // [b*h][d][n]
  f16* O = (f16*)p;     p += (size_t)4096 * 1024 * 2;      // [b*n][h*64+d]

  k_cvt<<<4096, 256, 0, stream>>>((const float4*)x, (f16x4*)Xb, 4096 * 1024 / 4);
  k_transpose_qkv<<<dim3(96, 32), dim3(32, 8), 0, stream>>>(Wqkv, Wqkvt);
  k_transpose<<<dim3(32, 32), dim3(32, 8), 0, stream>>>(Wout, Woutt, 1024, 1024);
  k_gemm<0><<<dim3(24, 32), 256, 0, stream>>>(Xb, Wqkvt, nullptr, Qp, Kp, Vt);
  k_attn<<<512, 256, 0, stream>>>(Qp, Kp, Vt, O);
  k_gemm<1><<<dim3(8, 32), 256, 0, stream>>>(O, Woutt, (float*)d_out, nullptr, nullptr, nullptr);
}

// Round 8
// 229.285 us; speedup vs baseline: 1.1001x; 1.0044x over previous
//
#include <hip/hip_runtime.h>

typedef _Float16 f16;
typedef f16 half8 __attribute__((ext_vector_type(8)));
typedef f16 f16x4 __attribute__((ext_vector_type(4)));
typedef float f32x4 __attribute__((ext_vector_type(4)));

#define GLOAD_LDS16(gsrc, ldst)                                                              \
  __builtin_amdgcn_global_load_lds((const __attribute__((address_space(1))) void*)(gsrc),    \
                                   (__attribute__((address_space(3))) void*)(ldst), 16, 0, 0)

constexpr float SCALE = 0.125f;  // 64^-0.5
// Q pre-scale folds log2(e): softmax runs in exp2 domain (raw v_exp_f32).
constexpr float SCALE_L2E = 0.125f * 1.4426950408889634f;

// pack two f32 -> two f16 in one u32 (v_cvt_pkrtz_f16_f32); bit_cast fixes the
// __fp16-vs-_Float16 ext-vector type mismatch (round 7 compile error).
static __device__ __forceinline__ unsigned pk2(float a, float b) {
  return __builtin_bit_cast(unsigned, __builtin_amdgcn_cvt_pkrtz(a, b));
}

// ---------------- convert f32 -> f16, vectorized x4 ----------------
__global__ __launch_bounds__(256) void k_cvt(const float4* __restrict__ in,
                                             f16x4* __restrict__ out, int n4) {
  int i = blockIdx.x * 256 + threadIdx.x;
  if (i < n4) {
    float4 v = in[i];
    f16x4 o;
    o[0] = (f16)v.x; o[1] = (f16)v.y; o[2] = (f16)v.z; o[3] = (f16)v.w;
    out[i] = o;
  }
}

// ---------------- transpose f32 [R][C] -> f16 [C][R] (generic, for W_out) ----
__global__ __launch_bounds__(256) void k_transpose(const float* __restrict__ in,
                                                   f16* __restrict__ out, int R, int C) {
  __shared__ float t[32][33];
  int c0 = blockIdx.x * 32, r0 = blockIdx.y * 32;
  int tx = threadIdx.x, ty = threadIdx.y;
  for (int i = ty; i < 32; i += 8) t[i][tx] = in[(size_t)(r0 + i) * C + c0 + tx];
  __syncthreads();
  for (int i = ty; i < 32; i += 8) out[(size_t)(c0 + i) * R + r0 + tx] = (f16)t[tx][i];
}

// -------- W_qkv transpose with column-permuted output row order ----------
// out row e' = k*1024 + h*64 + d  (kills epilogue write amplification).
__global__ __launch_bounds__(256) void k_transpose_qkv(const float* __restrict__ in,
                                                       f16* __restrict__ out) {
  __shared__ float t[32][33];
  int c0 = blockIdx.x * 32, r0 = blockIdx.y * 32;
  int tx = threadIdx.x, ty = threadIdx.y;
  for (int i = ty; i < 32; i += 8) t[i][tx] = in[(size_t)(r0 + i) * 3072 + c0 + tx];
  __syncthreads();
  for (int i = ty; i < 32; i += 8) {
    const int e = c0 + i;
    const int d = e / 48, rem = e - d * 48;
    const int k = rem >> 4, h = rem & 15;
    const int ep = k * 1024 + h * 64 + d;
    out[(size_t)ep * 1024 + r0 + tx] = (f16)t[tx][i];
  }
}

// ---------------- GEMM (unchanged) ----------------
template <int MODE>
__global__ __launch_bounds__(256) void k_gemm(const f16* __restrict__ A,
                                              const f16* __restrict__ Bt,
                                              float* __restrict__ C,
                                              f16* __restrict__ Qp,
                                              f16* __restrict__ Kp,
                                              f16* __restrict__ Vt) {
  constexpr int K = 1024, BK = 64;
  __shared__ alignas(16) f16 smem[128 * 128];
  f16* As = smem;
  f16* Bs = smem + 128 * 64;
  const int tid = threadIdx.x;
  const int w = tid >> 6, lane = tid & 63;
  const int g = lane >> 4, lr = lane & 15;
  const int wr = w >> 1, wc = w & 1;
  const int m0 = blockIdx.y * 128, n0 = blockIdx.x * 128;
  const int srow = lane >> 3;
  const int scol = ((lane & 7) ^ srow) << 3;

  f32x4 acc[4][4] = {};

  for (int kt = 0; kt < K; kt += BK) {
    __syncthreads();
#pragma unroll
    for (int i = 0; i < 4; ++i) {
      const int chunk = w * 4 + i;
      const int row = chunk * 8 + srow;
      GLOAD_LDS16(A + (size_t)(m0 + row) * K + kt + scol, &As[chunk * 512]);
      GLOAD_LDS16(Bt + (size_t)(n0 + row) * K + kt + scol, &Bs[chunk * 512]);
    }
    __syncthreads();
#pragma unroll
    for (int c = 0; c < 2; ++c) {
      half8 af[4], bf[4];
#pragma unroll
      for (int m = 0; m < 4; ++m) {
        const int ra = wr * 64 + m * 16 + lr;
        const int off = ra * 128 + ((((c << 2) | g) ^ (ra & 7)) << 4);
        af[m] = *(const half8*)((const char*)As + off);
      }
#pragma unroll
      for (int n = 0; n < 4; ++n) {
        const int rb = wc * 64 + n * 16 + lr;
        const int off = rb * 128 + ((((c << 2) | g) ^ (rb & 7)) << 4);
        bf[n] = *(const half8*)((const char*)Bs + off);
      }
#pragma unroll
      for (int m = 0; m < 4; ++m)
#pragma unroll
        for (int n = 0; n < 4; ++n)
          acc[m][n] = __builtin_amdgcn_mfma_f32_16x16x32_f16(af[m], bf[n], acc[m][n], 0, 0, 0);
    }
  }

  if constexpr (MODE == 0) {
    const int sec = n0 >> 10;
    const int base = n0 & 1023;
    const int b = m0 >> 11;
    if (sec < 2) {
      f16* __restrict__ dst = (sec == 0) ? Qp : Kp;
      const float mul = (sec == 0) ? SCALE_L2E : 1.0f;
#pragma unroll
      for (int n = 0; n < 4; ++n) {
        const int idx = base + wc * 64 + n * 16 + lr;
        const int h = idx >> 6, d = idx & 63;
        f16* __restrict__ dh = dst + ((size_t)(b * 16 + h) * 2048) * 64 + d;
#pragma unroll
        for (int m = 0; m < 4; ++m)
#pragma unroll
          for (int r = 0; r < 4; ++r) {
            const int nn = (m0 & 2047) + wr * 64 + m * 16 + 4 * g + r;
            dh[(size_t)nn * 64] = (f16)(acc[m][n][r] * mul);
          }
      }
    } else {
      char* sb = (char*)smem;
      __syncthreads();
#pragma unroll
      for (int m = 0; m < 4; ++m)
#pragma unroll
        for (int n = 0; n < 4; ++n) {
          const int col = wc * 64 + n * 16 + lr;
          const int tok0 = wr * 64 + m * 16 + 4 * g;
          f16x4 v4;
#pragma unroll
          for (int r = 0; r < 4; ++r) v4[r] = (f16)acc[m][n][r];
          *(f16x4*)(sb + col * 256 + ((tok0 * 2) ^ ((col & 15) << 4))) = v4;
        }
      __syncthreads();
      const int nn0 = m0 & 2047;
#pragma unroll
      for (int pass = 0; pass < 8; ++pass) {
        const int c = w * 32 + pass * 4 + g;
        const int idx = base + c;
        const int h = idx >> 6, d = idx & 63;
        const half8 v = *(const half8*)(sb + c * 256 + ((lr * 16) ^ ((c & 15) << 4)));
        *(half8*)(Vt + ((size_t)(b * 16 + h) * 64 + d) * 2048 + nn0 + lr * 8) = v;
      }
    }
  } else {
#pragma unroll
    for (int m = 0; m < 4; ++m)
#pragma unroll
      for (int n = 0; n < 4; ++n)
#pragma unroll
        for (int r = 0; r < 4; ++r)
          C[(size_t)(m0 + wr * 64 + m * 16 + 4 * g + r) * 1024 +
            (n0 + wc * 64 + n * 16 + lr)] = acc[m][n][r];
  }
}

// ---------------- causal flash attention v5 ----------------
// Swapped-operand core: S^T = mfma(K,Q) puts each q-row in-lane (q = lane&15):
// softmax = in-lane trees + 2 single-depth shfl_xor; rescale/normalize in-lane.
// PV computes O^T = V^T * P^T; P reaches the B-operand via a packed padded-LDS
// roundtrip (pk2 b32 writes, b128 reads, 2-way banks). No block barriers:
// block = 2 INDEPENDENT equal-length waves (q-tiles 2j,2j+1 of one head, both
// j+1 K-tiles, shared K/V L2 locality). Grid 1024, LPT order (longest j first),
// bh = g&31 -> 4 heads per XCD L2. Coalesced O write via end LDS transpose.
__global__ __launch_bounds__(128, 3) void k_attn(const f16* __restrict__ Q,
                                                 const f16* __restrict__ Kp,
                                                 const f16* __restrict__ Vt,
                                                 f16* __restrict__ O) {
  __shared__ alignas(16) char plds_all[2][4608];  // per wave [32 rows][144 B]
  const int tid = threadIdx.x;
  const int w = tid >> 6, lane = tid & 63;
  const int g = lane >> 4, lr = lane & 15;
  const int gb = blockIdx.x;
  const int j = 31 - (gb >> 5);  // LPT: longest first
  const int bh = gb & 31;
  const int q0 = (2 * j + w) * 32;
  char* pl = plds_all[w];

  const f16* __restrict__ Qb = Q + (size_t)bh * (2048 * 64);
  const f16* __restrict__ Kb = Kp + (size_t)bh * (2048 * 64);
  const f16* __restrict__ Vb = Vt + (size_t)bh * (64 * 2048);

  // Q as B-operand: col = lr -> q-row q0+16f+lr, k = 8g+i -> d
  half8 qf[2][2];
#pragma unroll
  for (int f = 0; f < 2; ++f)
#pragma unroll
    for (int c = 0; c < 2; ++c)
      qf[f][c] = *(const half8*)(Qb + (size_t)(q0 + 16 * f + lr) * 64 + 32 * c + 8 * g);

  f32x4 acc[2][4] = {};  // O^T: acc[f][nb][r] = O^T[d=16nb+4g+r][q=q0+16f+lr]
  float mrow[2] = {-INFINITY, -INFINITY};
  float lrow[2] = {0.f, 0.f};

  for (int kt = 0; kt <= j; ++kt) {
    const int k0 = kt * 64;
    // K as A-operand: row = lr -> key k0+16jj+lr, k = 8g+i -> d
    half8 kf[4][2];
#pragma unroll
    for (int jj = 0; jj < 4; ++jj)
#pragma unroll
      for (int c = 0; c < 2; ++c)
        kf[jj][c] = *(const half8*)(Kb + (size_t)(k0 + 16 * jj + lr) * 64 + 32 * c + 8 * g);

    // ---- S^T = K Q^T : lane holds S^T[key=k0+16jj+4g+r][q=q0+16f+lr] ----
    __builtin_amdgcn_s_setprio(1);
    f32x4 st[2][4];
#pragma unroll
    for (int f = 0; f < 2; ++f)
#pragma unroll
      for (int jj = 0; jj < 4; ++jj) {
        f32x4 z = {};
        z = __builtin_amdgcn_mfma_f32_16x16x32_f16(kf[jj][0], qf[f][0], z, 0, 0, 0);
        st[f][jj] = __builtin_amdgcn_mfma_f32_16x16x32_f16(kf[jj][1], qf[f][1], z, 0, 0, 0);
      }
    __builtin_amdgcn_s_setprio(0);

    // V as A-operand (issued early; latency hides under softmax):
    // row = lr -> d = 16nb+lr, k = 8g+i -> key
    half8 va[4][2];
#pragma unroll
    for (int nb = 0; nb < 4; ++nb)
#pragma unroll
      for (int c = 0; c < 2; ++c)
        va[nb][c] = *(const half8*)(Vb + (size_t)(16 * nb + lr) * 2048 + k0 + 32 * c + 8 * g);

    // causal mask (only the diagonal tile triggers)
    if (k0 + 63 > q0) {
#pragma unroll
      for (int f = 0; f < 2; ++f)
#pragma unroll
        for (int jj = 0; jj < 4; ++jj) {
          const int keyb = k0 + 16 * jj + 4 * g;
          const int q = q0 + 16 * f + lr;
#pragma unroll
          for (int r = 0; r < 4; ++r)
            if (keyb + r > q) st[f][jj][r] = -INFINITY;
        }
    }

    // ---- in-lane online softmax (exp2 domain) + packed P write ----
    float sfv[2];
#pragma unroll
    for (int f = 0; f < 2; ++f) {
      f32x4 m4 = st[f][0];
#pragma unroll
      for (int jj = 1; jj < 4; ++jj)
#pragma unroll
        for (int r = 0; r < 4; ++r) m4[r] = fmaxf(m4[r], st[f][jj][r]);
      float tm = fmaxf(fmaxf(m4[0], m4[1]), fmaxf(m4[2], m4[3]));
      tm = fmaxf(tm, __shfl_xor(tm, 16));
      tm = fmaxf(tm, __shfl_xor(tm, 32));
      const float mn = fmaxf(mrow[f], tm);
      sfv[f] = __builtin_amdgcn_exp2f(mrow[f] - mn);
      mrow[f] = mn;
      f32x4 s4 = {};
#pragma unroll
      for (int jj = 0; jj < 4; ++jj) {
#pragma unroll
        for (int r = 0; r < 4; ++r) {
          st[f][jj][r] = __builtin_amdgcn_exp2f(st[f][jj][r] - mn);
          s4[r] += st[f][jj][r];
        }
        // pack 4 keys -> 2x b32, write P^T -> [q-row][key] (row stride 144B)
        const int rb = (16 * f + lr) * 144 + 32 * jj + 8 * g;
        *(unsigned*)(pl + rb) = pk2(st[f][jj][0], st[f][jj][1]);
        *(unsigned*)(pl + rb + 4) = pk2(st[f][jj][2], st[f][jj][3]);
      }
      float rs = (s4[0] + s4[1]) + (s4[2] + s4[3]);
      rs += __shfl_xor(rs, 16);
      rs += __shfl_xor(rs, 32);
      lrow[f] = lrow[f] * sfv[f] + rs;
      // rescale O^T accumulator: sf is per-q = per-lane, pure in-lane
#pragma unroll
      for (int nb = 0; nb < 4; ++nb)
#pragma unroll
        for (int r = 0; r < 4; ++r) acc[f][nb][r] *= sfv[f];
    }

    asm volatile("s_waitcnt lgkmcnt(0)" ::: "memory");
    __builtin_amdgcn_sched_barrier(0);
    // P^T as B-operand: col = lr -> q, k = 8g+i -> key 32c+8g+i
    half8 pf[2][2];
#pragma unroll
    for (int f = 0; f < 2; ++f)
#pragma unroll
      for (int c = 0; c < 2; ++c)
        pf[f][c] = *(const half8*)(pl + (16 * f + lr) * 144 + 64 * c + 16 * g);

    __builtin_amdgcn_s_setprio(1);
#pragma unroll
    for (int f = 0; f < 2; ++f)
#pragma unroll
      for (int nb = 0; nb < 4; ++nb) {
        acc[f][nb] = __builtin_amdgcn_mfma_f32_16x16x32_f16(va[nb][0], pf[f][0], acc[f][nb], 0, 0, 0);
        acc[f][nb] = __builtin_amdgcn_mfma_f32_16x16x32_f16(va[nb][1], pf[f][1], acc[f][nb], 0, 0, 0);
      }
    __builtin_amdgcn_s_setprio(0);
    __builtin_amdgcn_sched_barrier(0);  // P reads precede next tile's writes
  }

  // ---- normalize (in-lane) + O^T -> O transpose via LDS, coalesced store ----
#pragma unroll
  for (int f = 0; f < 2; ++f) {
    const float inv = 1.f / lrow[f];
#pragma unroll
    for (int nb = 0; nb < 4; ++nb) {
      const int rb = (16 * f + lr) * 144 + 32 * nb + 8 * g;
      *(unsigned*)(pl + rb) = pk2(acc[f][nb][0] * inv, acc[f][nb][1] * inv);
      *(unsigned*)(pl + rb + 4) = pk2(acc[f][nb][2] * inv, acc[f][nb][3] * inv);
    }
  }
  asm volatile("s_waitcnt lgkmcnt(0)" ::: "memory");
  __builtin_amdgcn_sched_barrier(0);
  const int b = bh >> 4, h = bh & 15;
  const int row = lane >> 1, half = lane & 1;  // 2 lanes per q-row
  f16* orow = O + ((size_t)(b * 2048 + q0 + row) * 1024) + h * 64 + 32 * half;
#pragma unroll
  for (int k = 0; k < 4; ++k) {
    const half8 v = *(const half8*)(pl + row * 144 + 64 * half + 16 * k);
    *(half8*)(orow + 8 * k) = v;
  }
}

extern "C" void kernel_launch(void* const* d_in, const int* in_sizes, int n_in,
                              void* d_out, int out_size, void* d_ws, size_t ws_size,
                              hipStream_t stream) {
  const float* x = (const float*)d_in[0];     // [2][2048][1024]
  const float* Wqkv = (const float*)d_in[1];  // [1024][3072]
  const float* Wout = (const float*)d_in[2];  // [1024][1024]

  char* p = (char*)d_ws;
  f16* Xb = (f16*)p;    p += (size_t)4096 * 1024 * 2;      // x in f16
  f16* Wqkvt = (f16*)p; p += (size_t)3072 * 1024 * 2;      // W_qkv^T f16, rows e'=[k][h][d]
  f16* Woutt = (f16*)p; p += (size_t)1024 * 1024 * 2;      // W_out^T f16
  f16* Qp = (f16*)p;    p += (size_t)32 * 2048 * 64 * 2;   // [b*h][n][d], scaled 1/8*log2e
  f16* Kp = (f16*)p;    p += (size_t)32 * 2048 * 64 * 2;   // [b*h][n][d]
  f16* Vt = (f16*)p;    p += (size_t)32 * 64 * 2048 * 2;   // [b*h][d][n]
  f16* O = (f16*)p;     p += (size_t)4096 * 1024 * 2;      // [b*n][h*64+d]

  k_cvt<<<4096, 256, 0, stream>>>((const float4*)x, (f16x4*)Xb, 4096 * 1024 / 4);
  k_transpose_qkv<<<dim3(96, 32), dim3(32, 8), 0, stream>>>(Wqkv, Wqkvt);
  k_transpose<<<dim3(32, 32), dim3(32, 8), 0, stream>>>(Wout, Woutt, 1024, 1024);
  k_gemm<0><<<dim3(24, 32), 256, 0, stream>>>(Xb, Wqkvt, nullptr, Qp, Kp, Vt);
  k_attn<<<1024, 128, 0, stream>>>(Qp, Kp, Vt, O);
  k_gemm<1><<<dim3(8, 32), 256, 0, stream>>>(O, Woutt, (float*)d_out, nullptr, nullptr, nullptr);
}